// Round 1
// baseline (7289.539 us; speedup 1.0000x reference)
//
#include <hip/hip_runtime.h>
#include <stdint.h>

#define B_  8
#define H_  128
#define W_  256
#define C_  96
#define HW_ (H_*W_)
#define ROWS_PER_SIDE (B_*HW_)      // 262144
#define TOT (ROWS_PER_SIDE*C_)      // 25165824 floats per output tensor

// ---------- bf16 helpers (manual RNE pack, shift unpack) ----------
__device__ __forceinline__ uint16_t bfp(float x) {
    union { float f; uint32_t u; } a; a.f = x;
    uint32_t r = a.u + 0x7fffu + ((a.u >> 16) & 1u);
    return (uint16_t)(r >> 16);
}
__device__ __forceinline__ float blo(uint32_t u) {
    union { uint32_t i; float f; } a; a.i = u << 16; return a.f;
}
__device__ __forceinline__ float bhi(uint32_t u) {
    union { uint32_t i; float f; } a; a.i = u & 0xffff0000u; return a.f;
}

// =================== K1: LN + Q projection ===================
// One block = 32 rows of one side. Q[r][d] = sum_c LN(x[r])[c] * w[d][c] + bias[d]
__global__ __launch_bounds__(256) void k_ln_qproj(
    const float* __restrict__ feat, const float* __restrict__ g,
    const float* __restrict__ b, const float* __restrict__ w,
    const float* __restrict__ bias, float* __restrict__ qout)
{
    __shared__ float xs[32][100];
    __shared__ float ws[96][100];
    __shared__ float gs[96], bs[96], bias_s[96];
    __shared__ float mu[32], rsd[32];
    const int t = threadIdx.x;
    const long r0 = (long)blockIdx.x * 32;

    for (int i = 0; i < 36; ++i) {            // 9216 weights
        int idx = i * 256 + t;
        ws[idx / 96][idx % 96] = w[idx];
    }
    if (t < 96) { gs[t] = g[t]; bs[t] = b[t]; bias_s[t] = bias[t]; }
    for (int i = 0; i < 12; ++i) {             // 3072 x elems, coalesced
        int idx = i * 256 + t;
        xs[idx / 96][idx % 96] = feat[r0 * C_ + idx];
    }
    __syncthreads();
    if (t < 32) {
        float s = 0.f, s2 = 0.f;
        for (int c = 0; c < 96; ++c) { float v = xs[t][c]; s += v; s2 += v * v; }
        float m = s * (1.0f / 96.0f);
        float var = s2 * (1.0f / 96.0f) - m * m;
        mu[t] = m; rsd[t] = rsqrtf(var + 1e-6f);
    }
    __syncthreads();
    for (int i = 0; i < 12; ++i) {             // LN in place
        int idx = i * 256 + t; int r = idx / 96, c = idx % 96;
        xs[r][c] = (xs[r][c] - mu[r]) * rsd[r] * gs[c] + bs[c];
    }
    __syncthreads();
    {
        const int r = t & 31, d0 = (t >> 5) * 12;
        float acc[12];
#pragma unroll
        for (int j = 0; j < 12; ++j) acc[j] = bias_s[d0 + j];
        for (int c = 0; c < 96; c += 4) {
            const float4 xv = *(const float4*)&xs[r][c];
#pragma unroll
            for (int j = 0; j < 12; ++j) {
                const float4 wv = *(const float4*)&ws[d0 + j][c];
                acc[j] += xv.x * wv.x + xv.y * wv.y + xv.z * wv.z + xv.w * wv.w;
            }
        }
        __syncthreads();                        // everyone done reading xs
#pragma unroll
        for (int j = 0; j < 12; ++j) xs[r][d0 + j] = acc[j];
    }
    __syncthreads();
    for (int i = 0; i < 12; ++i) {              // coalesced store
        int idx = i * 256 + t;
        qout[r0 * C_ + idx] = xs[idx / 96][idx % 96];
    }
}

// =================== K2: dual-direction attention ===================
// One block = one (b,h) slice, 512 threads = 8 waves, each wave owns 32 q rows.
// LDS layout (bytes):
//  QL  bf16[256][98]  @0       50176
//  QR  bf16[256][98]  @50176   50176
//  XT  bf16[64][98]   @100352  12544
//  VT  bf16[96][72]   @112896  13824   (transposed: VT[d][v])
//  P   bf16[256][64]  @126720  32768
//  ML  f32 [8][32][2] @159488  2048
//  AL  f32 [8][32]    @161536  1024    -> total 162560 (<=160 KiB)
#define LDS_BYTES 162560

__global__ __launch_bounds__(512) void k_attn(
    const float* __restrict__ feat_l, const float* __restrict__ feat_r,
    const float* __restrict__ w_l2, const float* __restrict__ bias_l2,
    const float* __restrict__ w_r2, const float* __restrict__ bias_r2,
    const float* __restrict__ beta, const float* __restrict__ gamma,
    float* __restrict__ out)
{
    extern __shared__ char lds[];
    uint16_t* QL = (uint16_t*)(lds);
    uint16_t* QR = (uint16_t*)(lds + 50176);
    uint16_t* XT = (uint16_t*)(lds + 100352);
    uint16_t* VT = (uint16_t*)(lds + 112896);
    uint16_t* P  = (uint16_t*)(lds + 126720);
    float*    ML = (float*)(lds + 159488);
    float*    AL = (float*)(lds + 161536);

    const int t = threadIdx.x;
    const int wv = t >> 6, lane = t & 63;
    const long eb = (long)blockIdx.x * 256 * C_;   // slice element base

    // Stage Q_l / Q_r from d_out (written by K1) BEFORE any output writes.
    for (int i = 0; i < 48; ++i) {
        int idx = i * 512 + t;                      // 24576
        int r = idx / 96, c = idx % 96;
        QL[r * 98 + c] = bfp(out[eb + idx]);
        QR[r * 98 + c] = bfp(out[(long)TOT + eb + idx]);
    }
    __syncthreads();

    const int qw = wv * 32;

    for (int dir = 0; dir < 2; ++dir) {
        const uint16_t* Q = dir ? QR : QL;
        const uint16_t* K = dir ? QL : QR;
        const float* xv2  = dir ? feat_l : feat_r;   // V source side
        const float* w2   = dir ? w_l2 : w_r2;
        const float* b2   = dir ? bias_l2 : bias_r2;
        const float* mix  = dir ? gamma : beta;
        const float* xres = dir ? feat_r : feat_l;
        float* o = out + (dir ? (long)TOT : 0l) + eb;

        if (lane < 32) {
            ML[(qw + lane) * 2 + 0] = -1e30f;
            ML[(qw + lane) * 2 + 1] = 0.f;
        }
        float acc0[32], acc1[32];
#pragma unroll
        for (int q = 0; q < 32; ++q) { acc0[q] = 0.f; acc1[q] = 0.f; }

        for (int vt = 0; vt < 4; ++vt) {
            const int v0 = vt * 64;
            __syncthreads();
            // ---- stage X tile (64 rows of V-source side) ----
            for (int i = 0; i < 12; ++i) {
                int idx = i * 512 + t;              // 6144
                int v = idx / 96, c = idx % 96;
                XT[v * 98 + c] = bfp(xv2[eb + (long)v0 * 96 + idx]);
            }
            __syncthreads();
            // ---- project V tile: VT[d][v] = sum_c XT[v][c]*w2[d][c] + b2[d] ----
            {
                const int v = lane;
                const int d0 = wv * 12;
                float pacc[12];
#pragma unroll
                for (int j = 0; j < 12; ++j) pacc[j] = 0.f;
                for (int cp = 0; cp < 48; ++cp) {
                    uint32_t xp = *(const uint32_t*)&XT[v * 98 + 2 * cp];
                    float x0 = blo(xp), x1 = bhi(xp);
#pragma unroll
                    for (int j = 0; j < 12; ++j) {
                        float2 wp = *(const float2*)&w2[(d0 + j) * 96 + 2 * cp];
                        pacc[j] += x0 * wp.x + x1 * wp.y;
                    }
                }
#pragma unroll
                for (int j = 0; j < 12; ++j)
                    VT[(d0 + j) * 72 + v] = bfp(pacc[j] + b2[d0 + j]);
            }
            __syncthreads();

            // ---- S phase: s[q][v0+lane], online softmax stats ----
            uint32_t kc[48];
#pragma unroll
            for (int i = 0; i < 48; ++i)
                kc[i] = *(const uint32_t*)&K[(v0 + lane) * 98 + 2 * i];
            for (int q = 0; q < 32; ++q) {
                float s = 0.f;
#pragma unroll
                for (int i = 0; i < 48; ++i) {
                    uint32_t qp = *(const uint32_t*)&Q[(qw + q) * 98 + 2 * i];
                    s += blo(qp) * blo(kc[i]) + bhi(qp) * bhi(kc[i]);
                }
                s *= 0.1020620726159658f;          // 96^-0.5
                float mt = s;
                for (int off = 32; off; off >>= 1) mt = fmaxf(mt, __shfl_xor(mt, off));
                float mo = ML[(qw + q) * 2 + 0];
                float mn = fmaxf(mo, mt);
                float al = __expf(mo - mn);
                float p  = __expf(s - mn);
                float ps = p;
                for (int off = 32; off; off >>= 1) ps += __shfl_xor(ps, off);
                if (lane == 0) {
                    ML[(qw + q) * 2 + 0] = mn;
                    ML[(qw + q) * 2 + 1] = ML[(qw + q) * 2 + 1] * al + ps;
                    AL[qw + q] = al;
                }
                P[(qw + q) * 64 + lane] = bfp(p);
            }
            __syncthreads();

            // ---- PV phase: acc[q][d] = acc*alpha + sum_v P[q][v]*VT[d][v] ----
            uint32_t vt0[32], vt1[32];
#pragma unroll
            for (int i = 0; i < 8; ++i) {
                uint4 a = *(const uint4*)&VT[lane * 72 + 8 * i];
                vt0[4*i+0] = a.x; vt0[4*i+1] = a.y; vt0[4*i+2] = a.z; vt0[4*i+3] = a.w;
            }
            {
                const int d1 = 64 + (lane & 31);   // lanes>=32 duplicate, never stored
#pragma unroll
                for (int i = 0; i < 8; ++i) {
                    uint4 a = *(const uint4*)&VT[d1 * 72 + 8 * i];
                    vt1[4*i+0] = a.x; vt1[4*i+1] = a.y; vt1[4*i+2] = a.z; vt1[4*i+3] = a.w;
                }
            }
#pragma unroll
            for (int q = 0; q < 32; ++q) {
                const float a = AL[qw + q];
                float s0 = acc0[q] * a, s1 = acc1[q] * a;
#pragma unroll
                for (int ch = 0; ch < 8; ++ch) {
                    uint4 pp = *(const uint4*)&P[(qw + q) * 64 + 8 * ch];
                    float p0, p1;
                    p0 = blo(pp.x); p1 = bhi(pp.x);
                    s0 += p0 * blo(vt0[4*ch+0]) + p1 * bhi(vt0[4*ch+0]);
                    s1 += p0 * blo(vt1[4*ch+0]) + p1 * bhi(vt1[4*ch+0]);
                    p0 = blo(pp.y); p1 = bhi(pp.y);
                    s0 += p0 * blo(vt0[4*ch+1]) + p1 * bhi(vt0[4*ch+1]);
                    s1 += p0 * blo(vt1[4*ch+1]) + p1 * bhi(vt1[4*ch+1]);
                    p0 = blo(pp.z); p1 = bhi(pp.z);
                    s0 += p0 * blo(vt0[4*ch+2]) + p1 * bhi(vt0[4*ch+2]);
                    s1 += p0 * blo(vt1[4*ch+2]) + p1 * bhi(vt1[4*ch+2]);
                    p0 = blo(pp.w); p1 = bhi(pp.w);
                    s0 += p0 * blo(vt0[4*ch+3]) + p1 * bhi(vt0[4*ch+3]);
                    s1 += p0 * blo(vt1[4*ch+3]) + p1 * bhi(vt1[4*ch+3]);
                }
                acc0[q] = s0; acc1[q] = s1;
            }
        }
        __syncthreads();

        // ---- epilogue: out = x + (acc/l)*mix ----
#pragma unroll
        for (int q = 0; q < 32; ++q) {
            float l = ML[(qw + q) * 2 + 1];
            float inv = 1.0f / l;
            long ro = (long)(qw + q) * 96;
            o[ro + lane] = xres[eb + ro + lane] + acc0[q] * inv * mix[lane];
            if (lane < 32)
                o[ro + 64 + lane] = xres[eb + ro + 64 + lane]
                                  + acc1[q] * inv * mix[64 + lane];
        }
        __syncthreads();
    }
}

extern "C" void kernel_launch(void* const* d_in, const int* in_sizes, int n_in,
                              void* d_out, int out_size, void* d_ws, size_t ws_size,
                              hipStream_t stream) {
    const float* feat_l  = (const float*)d_in[0];
    const float* feat_r  = (const float*)d_in[1];
    const float* g_nl    = (const float*)d_in[2];
    const float* b_nl    = (const float*)d_in[3];
    const float* g_nr    = (const float*)d_in[4];
    const float* b_nr    = (const float*)d_in[5];
    const float* w_l1    = (const float*)d_in[6];
    const float* bias_l1 = (const float*)d_in[7];
    const float* w_r1    = (const float*)d_in[8];
    const float* bias_r1 = (const float*)d_in[9];
    const float* w_l2    = (const float*)d_in[10];
    const float* bias_l2 = (const float*)d_in[11];
    const float* w_r2    = (const float*)d_in[12];
    const float* bias_r2 = (const float*)d_in[13];
    const float* beta    = (const float*)d_in[14];
    const float* gamma   = (const float*)d_in[15];
    float* out = (float*)d_out;

    dim3 b1(256), g1(ROWS_PER_SIDE / 32);
    hipLaunchKernelGGL(k_ln_qproj, g1, b1, 0, stream,
                       feat_l, g_nl, b_nl, w_l1, bias_l1, out);
    hipLaunchKernelGGL(k_ln_qproj, g1, b1, 0, stream,
                       feat_r, g_nr, b_nr, w_r1, bias_r1, out + (long)TOT);

    dim3 b2(512), g2(B_ * H_);
    hipLaunchKernelGGL(k_attn, g2, b2, LDS_BYTES, stream,
                       feat_l, feat_r, w_l2, bias_l2, w_r2, bias_r2,
                       beta, gamma, out);
}

// Round 2
// 266.602 us; speedup vs baseline: 27.3424x; 27.3424x over previous
//
#include <hip/hip_runtime.h>
#include <stdint.h>

#define C96   96
#define SROWS 256
#define TOTEL 25165824L   // 8*128*256*96

typedef __attribute__((ext_vector_type(16))) float f32x16;
typedef __attribute__((ext_vector_type(8)))  short short8;

// ---- LDS layout (bytes). Row stride for [*][96] bf16 tiles = 104 elems (208 B):
//      208 % 16 == 0 (b128-aligned) and 52-word stride -> 8-bank period -> 2-way (free).
#define QL_OFF 0         // [256][104] bf16 = 53248
#define QR_OFF 53248     // [256][104] bf16 = 53248
#define SC_OFF 106496    // scratch: phase1 raw X [256][104]; attn: XT+VT
#define XT_OFF SC_OFF               // [64][104] bf16 = 13312
#define VT_OFF (SC_OFF + 13312)     // V^T [96][72] bf16 = 13824 (144B rows, b128 ok)
#define ST_OFF 159744    // stats [256]{mu,rs} f32 = 2048
#define LDS_SZ 161792

#define MFMA32(a,b,c) __builtin_amdgcn_mfma_f32_32x32x16_bf16(a,b,c,0,0,0)

__device__ __forceinline__ uint32_t cvtpk(float lo, float hi) {
    uint32_t d;
    asm("v_cvt_pk_bf16_f32 %0, %1, %2" : "=v"(d) : "v"(lo), "v"(hi));
    return d;
}
__device__ __forceinline__ float bl(uint32_t u){ union{uint32_t i;float f;}a; a.i=u<<16;        return a.f; }
__device__ __forceinline__ float bh(uint32_t u){ union{uint32_t i;float f;}a; a.i=u&0xffff0000u; return a.f; }

union F8 { uint32_t u[4]; short8 s; uint4 q; };

// coalesced global f32 -> LDS bf16 rows (stride 104 elems)
template<int ITERS>
__device__ __forceinline__ void stage(const float* __restrict__ src, char* dst, int t) {
#pragma unroll
    for (int i = 0; i < ITERS; ++i) {
        const int idx4 = i * 512 + t;
        const float4 v = *(const float4*)(src + (size_t)idx4 * 4);
        const int r = idx4 / 24;          // (idx4*4)/96
        const int c = (idx4 % 24) * 4;
        uint2 p; p.x = cvtpk(v.x, v.y); p.y = cvtpk(v.z, v.w);
        *(uint2*)(dst + r * 208 + c * 2) = p;
    }
}

__device__ __forceinline__ void ln_stats(char* lds, int t) {
    if (t < 256) {
        const char* row = lds + SC_OFF + t * 208;
        float sm = 0.f, s2 = 0.f;
#pragma unroll
        for (int i = 0; i < 12; ++i) {
            F8 w; w.q = *(const uint4*)(row + i * 16);
#pragma unroll
            for (int j = 0; j < 4; ++j) {
                const float a = bl(w.u[j]), b = bh(w.u[j]);
                sm += a + b; s2 += a * a + b * b;
            }
        }
        const float mu = sm * (1.f / 96.f);
        float var = s2 * (1.f / 96.f) - mu * mu;
        var = fmaxf(var, 0.f);
        const float rs = rsqrtf(var + 1e-6f);
        *(float2*)(lds + ST_OFF + t * 8) = make_float2(mu, rs);
    }
}

// Q^T = W1 * LN(X)^T via 32x32x16 MFMA. LN fused into B-fragment load.
__device__ __forceinline__ void qproj(
    char* lds, char* qdst,
    const float* __restrict__ W1, const float* __restrict__ bias1,
    const float* __restrict__ gv, const float* __restrict__ bv,
    float outscale, int wv, int l31, int s)
{
    const int r = wv * 32 + l31;
    const float2 st = *(const float2*)(lds + ST_OFF + r * 8);
    const float mu = st.x, rs = st.y;
    short8 bfrag[6];
#pragma unroll
    for (int kf = 0; kf < 6; ++kf) {
        const int c0 = kf * 16 + s * 8;
        F8 raw; raw.q = *(const uint4*)(lds + SC_OFF + r * 208 + c0 * 2);
        const float4 g0 = *(const float4*)(gv + c0);
        const float4 g1 = *(const float4*)(gv + c0 + 4);
        const float4 b0 = *(const float4*)(bv + c0);
        const float4 b1 = *(const float4*)(bv + c0 + 4);
        const float x0=bl(raw.u[0]),x1=bh(raw.u[0]),x2=bl(raw.u[1]),x3=bh(raw.u[1]);
        const float x4=bl(raw.u[2]),x5=bh(raw.u[2]),x6=bl(raw.u[3]),x7=bh(raw.u[3]);
        F8 o;
        o.u[0] = cvtpk((x0-mu)*rs*g0.x + b0.x, (x1-mu)*rs*g0.y + b0.y);
        o.u[1] = cvtpk((x2-mu)*rs*g0.z + b0.z, (x3-mu)*rs*g0.w + b0.w);
        o.u[2] = cvtpk((x4-mu)*rs*g1.x + b1.x, (x5-mu)*rs*g1.y + b1.y);
        o.u[3] = cvtpk((x6-mu)*rs*g1.z + b1.z, (x7-mu)*rs*g1.w + b1.w);
        bfrag[kf] = o.s;
    }
    f32x16 qa[3];
#pragma unroll
    for (int i = 0; i < 16; ++i) { qa[0][i] = 0.f; qa[1][i] = 0.f; qa[2][i] = 0.f; }
#pragma unroll
    for (int kf = 0; kf < 6; ++kf) {
        const int cc = kf * 16 + s * 8;
#pragma unroll
        for (int mf = 0; mf < 3; ++mf) {
            const float* wp = W1 + (mf * 32 + l31) * 96 + cc;
            const float4 a0 = *(const float4*)wp;
            const float4 a1 = *(const float4*)(wp + 4);
            F8 af;
            af.u[0] = cvtpk(a0.x, a0.y); af.u[1] = cvtpk(a0.z, a0.w);
            af.u[2] = cvtpk(a1.x, a1.y); af.u[3] = cvtpk(a1.z, a1.w);
            qa[mf] = MFMA32(af.s, bfrag[kf], qa[mf]);
        }
    }
#pragma unroll
    for (int mf = 0; mf < 3; ++mf) {
#pragma unroll
        for (int rq = 0; rq < 4; ++rq) {
            const int d = mf * 32 + rq * 8 + s * 4;
            const float4 bb = *(const float4*)(bias1 + d);
            uint2 p;
            p.x = cvtpk((qa[mf][rq*4+0] + bb.x) * outscale, (qa[mf][rq*4+1] + bb.y) * outscale);
            p.y = cvtpk((qa[mf][rq*4+2] + bb.z) * outscale, (qa[mf][rq*4+3] + bb.w) * outscale);
            *(uint2*)(qdst + r * 208 + d * 2) = p;
        }
    }
}

extern "C" __global__ __launch_bounds__(512, 2) void scam_fused(
    const float* __restrict__ feat_l, const float* __restrict__ feat_r,
    const float* __restrict__ g_nl, const float* __restrict__ b_nl,
    const float* __restrict__ g_nr, const float* __restrict__ b_nr,
    const float* __restrict__ w_l1, const float* __restrict__ bias_l1,
    const float* __restrict__ w_r1, const float* __restrict__ bias_r1,
    const float* __restrict__ w_l2, const float* __restrict__ bias_l2,
    const float* __restrict__ w_r2, const float* __restrict__ bias_r2,
    const float* __restrict__ beta, const float* __restrict__ gamma,
    float* __restrict__ out)
{
    extern __shared__ char lds[];
    const int t    = threadIdx.x;
    const int wv   = t >> 6;
    const int lane = t & 63;
    const int l31  = lane & 31;
    const int s    = lane >> 5;
    const size_t eb = (size_t)blockIdx.x * (SROWS * C96);

    // ================= phase 1: Q projections (LN fused) =================
    stage<12>(feat_l + eb, lds + SC_OFF, t);
    __syncthreads();
    ln_stats(lds, t);
    __syncthreads();
    qproj(lds, lds + QL_OFF, w_l1, bias_l1, g_nl, b_nl, 0.10206207261596577f, wv, l31, s);
    __syncthreads();
    stage<12>(feat_r + eb, lds + SC_OFF, t);
    __syncthreads();
    ln_stats(lds, t);
    __syncthreads();
    qproj(lds, lds + QR_OFF, w_r1, bias_r1, g_nr, b_nr, 1.0f, wv, l31, s);

    // ================= phase 2: dual-direction flash attention =================
    for (int dir = 0; dir < 2; ++dir) {
        const char* Qs = lds + (dir ? QR_OFF : QL_OFF);   // B-side: q rows
        const char* Ks = lds + (dir ? QL_OFF : QR_OFF);   // A-side: v rows
        const float* xv   = dir ? feat_l  : feat_r;       // V source
        const float* w2   = dir ? w_l2    : w_r2;
        const float* b2   = dir ? bias_l2 : bias_r2;
        const float* mixv = dir ? gamma   : beta;
        const float* xres = dir ? feat_r  : feat_l;
        float* o = out + (dir ? TOTEL : 0);

        // cache Q-side B-fragments (n = q = lane&31)
        short8 bq[6];
#pragma unroll
        for (int kf = 0; kf < 6; ++kf)
            bq[kf] = *(const short8*)(Qs + (wv * 32 + l31) * 208 + kf * 32 + s * 16);

        // cache W2 A-fragments for V projection (waves 0..5 own a 32x32 out-tile)
        short8 wf[6];
        const int mfv = wv % 3, nfv = wv / 3;
        if (wv < 6) {
#pragma unroll
            for (int kf = 0; kf < 6; ++kf) {
                const float* wp = w2 + (mfv * 32 + l31) * 96 + kf * 16 + s * 8;
                const float4 a0 = *(const float4*)wp;
                const float4 a1 = *(const float4*)(wp + 4);
                F8 af;
                af.u[0] = cvtpk(a0.x, a0.y); af.u[1] = cvtpk(a0.z, a0.w);
                af.u[2] = cvtpk(a1.x, a1.y); af.u[3] = cvtpk(a1.z, a1.w);
                wf[kf] = af.s;
            }
        }

        f32x16 O[3];
#pragma unroll
        for (int i = 0; i < 16; ++i) { O[0][i] = 0.f; O[1][i] = 0.f; O[2][i] = 0.f; }
        float m_run = -1e30f, l_run = 0.f;

        __syncthreads();                      // protect SC/XT from previous-phase readers
        stage<3>(xv + eb, lds + XT_OFF, t);   // prologue: tile 0

        for (int vt = 0; vt < 4; ++vt) {
            __syncthreads();                  // XT(vt) staged; VT free to overwrite
            // ---- V projection: V^T[d][v] for this tile ----
            if (wv < 6) {
                f32x16 va;
#pragma unroll
                for (int i = 0; i < 16; ++i) va[i] = 0.f;
#pragma unroll
                for (int kf = 0; kf < 6; ++kf) {
                    const short8 xb = *(const short8*)(lds + XT_OFF + (nfv * 32 + l31) * 208 + kf * 32 + s * 16);
                    va = MFMA32(wf[kf], xb, va);
                }
                const int v = nfv * 32 + l31;
#pragma unroll
                for (int rq = 0; rq < 4; ++rq) {
                    const int d = mfv * 32 + rq * 8 + s * 4;
                    const float4 bb = *(const float4*)(b2 + d);
                    *(uint16_t*)(lds + VT_OFF + (d+0) * 144 + v * 2) = (uint16_t)cvtpk(va[rq*4+0] + bb.x, 0.f);
                    *(uint16_t*)(lds + VT_OFF + (d+1) * 144 + v * 2) = (uint16_t)cvtpk(va[rq*4+1] + bb.y, 0.f);
                    *(uint16_t*)(lds + VT_OFF + (d+2) * 144 + v * 2) = (uint16_t)cvtpk(va[rq*4+2] + bb.z, 0.f);
                    *(uint16_t*)(lds + VT_OFF + (d+3) * 144 + v * 2) = (uint16_t)cvtpk(va[rq*4+3] + bb.w, 0.f);
                }
            }
            __syncthreads();                  // VT(vt) ready; XT(vt) dead
            if (vt < 3) stage<3>(xv + eb + (size_t)(vt + 1) * 64 * 96, lds + XT_OFF, t);

            // ---- S^T = K * Q^T (m = v rows, n = q cols) ----
            f32x16 sa[2];
#pragma unroll
            for (int i = 0; i < 16; ++i) { sa[0][i] = 0.f; sa[1][i] = 0.f; }
#pragma unroll
            for (int kf = 0; kf < 6; ++kf) {
                const short8 a0 = *(const short8*)(Ks + (vt * 64 +      l31) * 208 + kf * 32 + s * 16);
                const short8 a1 = *(const short8*)(Ks + (vt * 64 + 32 + l31) * 208 + kf * 32 + s * 16);
                sa[0] = MFMA32(a0, bq[kf], sa[0]);
                sa[1] = MFMA32(a1, bq[kf], sa[1]);
            }
            // ---- online softmax over v (lane-local 32 values + one half-swap) ----
            float tm = -1e30f;
#pragma unroll
            for (int i = 0; i < 16; ++i) { tm = fmaxf(tm, sa[0][i]); tm = fmaxf(tm, sa[1][i]); }
            tm = fmaxf(tm, __shfl_xor(tm, 32));
            const float mn = fmaxf(m_run, tm);
            const float al = __expf(m_run - mn);
            float ps = 0.f;
#pragma unroll
            for (int i = 0; i < 16; ++i) {
                sa[0][i] = __expf(sa[0][i] - mn); ps += sa[0][i];
                sa[1][i] = __expf(sa[1][i] - mn); ps += sa[1][i];
            }
            ps += __shfl_xor(ps, 32);
            l_run = l_run * al + ps;
            m_run = mn;
            O[0] *= al; O[1] *= al; O[2] *= al;

            // ---- PV: O^T += V^T * P^T; P fragments built in-register ----
#pragma unroll
            for (int kk = 0; kk < 4; ++kk) {
                const int mf = kk >> 1, base = (kk & 1) * 8;
                const uint32_t A0 = cvtpk(sa[mf][base+0], sa[mf][base+1]);
                const uint32_t A1 = cvtpk(sa[mf][base+2], sa[mf][base+3]);
                const uint32_t B0 = cvtpk(sa[mf][base+4], sa[mf][base+5]);
                const uint32_t B1 = cvtpk(sa[mf][base+6], sa[mf][base+7]);
                const uint32_t rA0 = __shfl_xor(A0, 32);
                const uint32_t rA1 = __shfl_xor(A1, 32);
                const uint32_t rB0 = __shfl_xor(B0, 32);
                const uint32_t rB1 = __shfl_xor(B1, 32);
                F8 pb;
                pb.u[0] = s ? rB0 : A0;
                pb.u[1] = s ? rB1 : A1;
                pb.u[2] = s ? B0  : rA0;
                pb.u[3] = s ? B1  : rA1;
#pragma unroll
                for (int mf2 = 0; mf2 < 3; ++mf2) {
                    const short8 av = *(const short8*)(lds + VT_OFF + (mf2 * 32 + l31) * 144 + kk * 32 + s * 16);
                    O[mf2] = MFMA32(av, pb.s, O[mf2]);
                }
            }
        }

        // ---- epilogue: out = x_res + (O/l) * mix ----
        const float inv = 1.f / l_run;
        const size_t rowbase = eb + (size_t)(wv * 32 + l31) * 96;
#pragma unroll
        for (int mf = 0; mf < 3; ++mf) {
#pragma unroll
            for (int rq = 0; rq < 4; ++rq) {
                const int d = mf * 32 + rq * 8 + s * 4;
                const float4 mx = *(const float4*)(mixv + d);
                const float4 xr = *(const float4*)(xres + rowbase + d);
                float4 ov;
                ov.x = fmaf(O[mf][rq*4+0] * inv, mx.x, xr.x);
                ov.y = fmaf(O[mf][rq*4+1] * inv, mx.y, xr.y);
                ov.z = fmaf(O[mf][rq*4+2] * inv, mx.z, xr.z);
                ov.w = fmaf(O[mf][rq*4+3] * inv, mx.w, xr.w);
                *(float4*)(o + rowbase + d) = ov;
            }
        }
    }
}

extern "C" void kernel_launch(void* const* d_in, const int* in_sizes, int n_in,
                              void* d_out, int out_size, void* d_ws, size_t ws_size,
                              hipStream_t stream) {
    const float* feat_l  = (const float*)d_in[0];
    const float* feat_r  = (const float*)d_in[1];
    const float* g_nl    = (const float*)d_in[2];
    const float* b_nl    = (const float*)d_in[3];
    const float* g_nr    = (const float*)d_in[4];
    const float* b_nr    = (const float*)d_in[5];
    const float* w_l1    = (const float*)d_in[6];
    const float* bias_l1 = (const float*)d_in[7];
    const float* w_r1    = (const float*)d_in[8];
    const float* bias_r1 = (const float*)d_in[9];
    const float* w_l2    = (const float*)d_in[10];
    const float* bias_l2 = (const float*)d_in[11];
    const float* w_r2    = (const float*)d_in[12];
    const float* bias_r2 = (const float*)d_in[13];
    const float* beta    = (const float*)d_in[14];
    const float* gamma   = (const float*)d_in[15];
    float* out = (float*)d_out;

    hipLaunchKernelGGL(scam_fused, dim3(1024), dim3(512), LDS_SZ, stream,
                       feat_l, feat_r, g_nl, b_nl, g_nr, b_nr,
                       w_l1, bias_l1, w_r1, bias_r1, w_l2, bias_l2, w_r2, bias_r2,
                       beta, gamma, out);
}